// Round 2
// baseline (290.959 us; speedup 1.0000x reference)
//
#include <hip/hip_runtime.h>
#include <cfloat>

static constexpr int kBS  = 512;
static constexpr int kL   = 68;
static constexpr int kIMG = 224;
static constexpr int kR2  = 49;
static constexpr int kLL  = kL * kL;  // 4624

// jnp.linspace(-3.5,3.5,7)[k]/224*2 — JAX convex-combination linspace,
// exact op order, no contraction. At k=6: step=1.0, a=-0.0, b=3.5 -> 3.5 exact.
__device__ __forceinline__ float lin_off_rt(int k) {
  float step = __fdiv_rn((float)k, 6.0f);
  float a = __fmul_rn(-3.5f, __fsub_rn(1.0f, step));
  float bb = __fmul_rn(3.5f, step);
  float x = __fadd_rn(a, bb);
  return __fmul_rn(__fdiv_rn(x, 224.0f), 2.0f);
}

// K1: one block per batch image b. 576 threads = 9 waves; 8 lanes per region,
// 8 regions per wave (72 slots, 68 used). Each lane holds 7 of the 49 samples.
// Then median-of-medians + mask for the whole b in the same block.
__global__ __launch_bounds__(576) void k_med_mask(
    const float* __restrict__ depth, const float* __restrict__ lmk,
    const float* __restrict__ scale, const float* __restrict__ bbox,
    float* __restrict__ m500, float* __restrict__ fm,
    unsigned long long* __restrict__ ctl) {
  __shared__ float med_s[kL];
  __shared__ float mom_s;
  int b = blockIdx.x;
  int tid = threadIdx.x;
  int wave = tid >> 6, lane = tid & 63;
  int g = lane >> 3, r = lane & 7;
  int lreg = wave * 8 + g;             // 0..71 local region
  int rr = min(lreg, kL - 1);          // clamp for loads (no OOB; dup work, no store)

  float lmx = lmk[(b * kL + rr) * 2 + 0];
  float lmy = lmk[(b * kL + rr) * 2 + 1];
  float sx = scale[b * 2 + 0], sy = scale[b * 2 + 1];
  float bx = bbox[b * 4 + 0],  by = bbox[b * 4 + 1];

  float tx = __fsub_rn(lmx, bx);
  tx = __fmul_rn(tx, sx); tx = __fdiv_rn(tx, 224.0f); tx = __fmul_rn(tx, 2.0f);
  float flmx = __fsub_rn(tx, 1.0f);
  float ty = __fsub_rn(lmy, by);
  ty = __fmul_rn(ty, sy); ty = __fdiv_rn(ty, 224.0f); ty = __fmul_rn(ty, 2.0f);
  float flmy = __fsub_rn(ty, 1.0f);

  const float* img = depth + (size_t)b * (kIMG * kIMG);
  float v[7];
#pragma unroll
  for (int s = 0; s < 7; ++s) {
    int idx = r + 8 * s;               // global sample index within region
    if (idx < kR2) {
      unsigned i7 = (unsigned)idx / 7u;
      int j7 = idx - (int)i7 * 7;
      float gx = __fadd_rn(flmx, lin_off_rt(j7));
      float gy = __fadd_rn(flmy, lin_off_rt((int)i7));
      float ix = __fmul_rn(__fsub_rn(__fmul_rn(__fadd_rn(gx, 1.0f), 224.0f), 1.0f), 0.5f);
      float iy = __fmul_rn(__fsub_rn(__fmul_rn(__fadd_rn(gy, 1.0f), 224.0f), 1.0f), 0.5f);
      int xi = (int)rintf(ix), yi = (int)rintf(iy);
      bool val = (xi >= 0) && (xi < kIMG) && (yi >= 0) && (yi < kIMG);
      int xc = min(max(xi, 0), kIMG - 1), yc = min(max(yi, 0), kIMG - 1);
      float dv = img[yc * kIMG + xc];
      v[s] = val ? dv : 0.0f;
    } else {
      v[s] = FLT_MAX;                  // pad sorts last, never selected/counted
    }
  }

  int rank[7] = {0, 0, 0, 0, 0, 0, 0};
  int cnt = 0;
  int gb = lane & 56;                  // group base lane
#pragma unroll
  for (int t = 0; t < 8; ++t) {
    float w[7];
#pragma unroll
    for (int s = 0; s < 7; ++s) w[s] = __shfl(v[s], gb + t, 64);
#pragma unroll
    for (int s = 0; s < 7; ++s) {
      const int widx = t + 8 * s;      // compile-time constant
      if (widx < kR2) cnt += (w[s] <= 1e-4f) ? 1 : 0;  // pads are +inf anyway
#pragma unroll
      for (int m = 0; m < 7; ++m) {
        // stable order: (value, global idx); idx_m = r + 8m
        bool less = (w[s] < v[m]) || ((w[s] == v[m]) && (widx < r + 8 * m));
        rank[m] += less ? 1 : 0;
      }
    }
  }
  // st = first sorted idx>=1 with s>THR (count of <=THR, clamped); fallback 48
  int st = min(max(cnt, 1), kR2 - 1);
  int kk = (st + kR2 - 1) >> 1;        // med_ind in [24,48]
  float sel = 0.0f;
#pragma unroll
  for (int m = 0; m < 7; ++m)
    if ((r + 8 * m) < kR2 && rank[m] == kk) sel = v[m];
  // exactly one lane/slot wins; depth >= 0 so OR of bits is exact
  int sb = __float_as_int(sel);
  sb |= __shfl_xor(sb, 1, 64);
  sb |= __shfl_xor(sb, 2, 64);
  sb |= __shfl_xor(sb, 4, 64);
  if (r == 0 && lreg < kL) med_s[lreg] = __int_as_float(sb);
  // zero the K2 control/ticket block (K2 is a later dispatch on the stream)
  if (b == 0 && tid >= 128 && tid < 144) ctl[tid - 128] = 0ull;
  __syncthreads();

  if (tid < kL) {
    float mv = med_s[tid];
    int rnk = 0;
    for (int j = 0; j < kL; ++j) {
      float vj = med_s[j];
      rnk += ((vj < mv) || (vj == mv && j < tid)) ? 1 : 0;
    }
    if (rnk == (kL - 1) / 2) mom_s = mv;  // lower median, exactly one thread
  }
  __syncthreads();
  if (tid < kL) {
    float mv = med_s[tid];
    float diff = fabsf(__fsub_rn(mv, mom_s));
    fm[b * kL + tid] = (diff < 0.18f) ? 1.0f : 0.0f;
    m500[b * kL + tid] = __fmul_rn(mv, 500.0f);
  }
}

// K2: [512,68,68] outputs + masked smooth-L1; last block (ticket) finishes loss.
__global__ __launch_bounds__(256) void k_out(
    const float* __restrict__ rdp, const float* __restrict__ m500,
    const float* __restrict__ fm, float* __restrict__ out_diff,
    float* __restrict__ out_mask, float* __restrict__ out0,
    unsigned long long* __restrict__ ctl, char* __restrict__ part) {
  __shared__ float s_m[kL], s_f[kL];
  __shared__ double sn[4], sd[4];
  __shared__ int lastFlag;
  int b = blockIdx.y, bx = blockIdx.x, t = threadIdx.x;
  if (t < kL) { s_m[t] = m500[b * kL + t]; s_f[t] = fm[b * kL + t]; }
  __syncthreads();

  int base = bx * 1156;                // 4 * 1156 = 4624
  double pn = 0.0, pd = 0.0;
#pragma unroll
  for (int k2 = 0; k2 < 5; ++k2) {
    int e = base + t + k2 * 256;
    if (e < base + 1156) {
      unsigned i = (unsigned)e / 68u;
      int j = e - (int)i * 68;
      float mi = s_m[i], mj = s_m[j];
      float diff = __fsub_rn(mi, mj);
      float mv = __fmul_rn(s_f[i], s_f[j]);
      size_t idx = (size_t)b * kLL + e;
      out_diff[idx] = diff;
      out_mask[idx] = mv;
      float d = __fsub_rn(rdp[idx], diff);
      float ad = fabsf(d);
      float le = (ad < 1.0f) ? __fmul_rn(__fmul_rn(0.5f, d), d)
                             : __fsub_rn(ad, 0.5f);
      pn += (double)__fmul_rn(le, mv);
      pd += (double)mv;
    }
  }
  for (int off = 32; off > 0; off >>= 1) {
    pn += __shfl_down(pn, off, 64);
    pd += __shfl_down(pd, off, 64);
  }
  int w = t >> 6;
  if ((t & 63) == 0) { sn[w] = pn; sd[w] = pd; }
  __syncthreads();
  int blkid = b * 4 + bx;              // 0..2047
  if (t == 0) {
    double tn = sn[0] + sn[1] + sn[2] + sn[3];
    double td = sd[0] + sd[1] + sd[2] + sd[3];
    double* pe = (double*)(part + (size_t)blkid * 128);  // 128B/block: no line sharing
    pe[0] = tn; pe[1] = td;
    __threadfence();                   // release (agent scope)
    unsigned old = atomicAdd((unsigned*)ctl, 1u);
    lastFlag = (old == 2047u);
  }
  __syncthreads();
  if (lastFlag) {
    __threadfence();                   // acquire
    double n = 0.0, dd = 0.0;
    for (int i = t; i < 2048; i += 256) {
      double* pe = (double*)(part + (size_t)i * 128);
      n += pe[0]; dd += pe[1];
    }
    for (int off = 32; off > 0; off >>= 1) {
      n += __shfl_down(n, off, 64);
      dd += __shfl_down(dd, off, 64);
    }
    if ((t & 63) == 0) { sn[t >> 6] = n; sd[t >> 6] = dd; }
    __syncthreads();
    if (t == 0) {
      double tn = sn[0] + sn[1] + sn[2] + sn[3];
      double td = sd[0] + sd[1] + sd[2] + sd[3];
      out0[0] = (float)(tn / (td + 1e-4));
    }
  }
}

extern "C" void kernel_launch(void* const* d_in, const int* in_sizes, int n_in,
                              void* d_out, int out_size, void* d_ws, size_t ws_size,
                              hipStream_t stream) {
  const float* rdp   = (const float*)d_in[0];  // [512,68,68]
  const float* depth = (const float*)d_in[1];  // [512,1,224,224]
  const float* lmk   = (const float*)d_in[2];  // [512,68,2]
  const float* scale = (const float*)d_in[3];  // [512,2]
  const float* bbox  = (const float*)d_in[4];  // [512,4]

  float* out = (float*)d_out;
  float* out_diff = out + 1;
  float* out_mask = out + 1 + (size_t)kBS * kLL;

  char* ws = (char*)d_ws;
  unsigned long long* ctl = (unsigned long long*)ws;          // 128 B
  float* m500 = (float*)(ws + 128);                           // 139264 B
  float* fm   = (float*)(ws + 128 + 139264);                  // 139264 B
  char*  part = ws + 128 + 2 * 139264;                        // 2048*128 B

  k_med_mask<<<dim3(kBS), dim3(576), 0, stream>>>(depth, lmk, scale, bbox,
                                                  m500, fm, ctl);
  k_out<<<dim3(4, kBS), dim3(256), 0, stream>>>(rdp, m500, fm, out_diff,
                                                out_mask, out, ctl, part);
}